// Round 7
// baseline (2992.390 us; speedup 1.0000x reference)
//
#include <hip/hip_runtime.h>
#include <cstdint>
#include <cstddef>

#define TPB 256

// ---------------- index-building kernels ----------------

static __global__ void kscatter(int* __restrict__ grid, const int* __restrict__ coords,
                                int N, int S) {
    int i = blockIdx.x * blockDim.x + threadIdx.x;
    if (i >= N) return;
    int x = coords[3 * i], y = coords[3 * i + 1], z = coords[3 * i + 2];
    grid[(x * S + y) * S + z] = i;
}

// invalid neighbors stay -1; conv staging zeroes them
static __global__ void knbr27(int* __restrict__ nbr, const int* __restrict__ coords,
                              const int* __restrict__ grid, int N, int S) {
    int t = blockIdx.x * blockDim.x + threadIdx.x;
    if (t >= N * 27) return;
    int n = t / 27, k = t - 27 * n;
    int x = coords[3 * n]     + (k / 9) - 1;
    int y = coords[3 * n + 1] + ((k / 3) % 3) - 1;
    int z = coords[3 * n + 2] + (k % 3) - 1;
    int v = -1;
    if ((unsigned)x < (unsigned)S && (unsigned)y < (unsigned)S && (unsigned)z < (unsigned)S)
        v = grid[(x * S + y) * S + z];
    nbr[t] = v;
}

static __global__ void kdown8(int* __restrict__ dn, const int* __restrict__ coords,
                              const int* __restrict__ grid, int M, int S_f) {
    int t = blockIdx.x * blockDim.x + threadIdx.x;
    if (t >= M * 8) return;
    int n = t >> 3, k = t & 7;
    int x = coords[3 * n] * 2     + ((k >> 2) & 1);
    int y = coords[3 * n + 1] * 2 + ((k >> 1) & 1);
    int z = coords[3 * n + 2] * 2 + (k & 1);
    dn[t] = grid[(x * S_f + y) * S_f + z];
}

static __global__ void kup(int* __restrict__ up, const int* __restrict__ cf,
                           const int* __restrict__ gc, int N, int Sc) {
    int n = blockIdx.x * blockDim.x + threadIdx.x;
    if (n >= N) return;
    int x = cf[3 * n] >> 2, y = cf[3 * n + 1] >> 2, z = cf[3 * n + 2] >> 2;
    up[n] = gc[(x * Sc + y) * Sc + z];       // parent always exists
}

// W[K][A][B] -> Wt[K][B][A]
static __global__ void ktrans(float* __restrict__ Wt, const float* __restrict__ W,
                              int K, int A, int B) {
    int t = blockIdx.x * blockDim.x + threadIdx.x;
    if (t >= K * A * B) return;
    int a = t % A, b = (t / A) % B, k = t / (A * B);
    Wt[t] = W[(k * A + a) * B + b];
}

// ---------------- BN stats ----------------

static __global__ void kstats(double* __restrict__ st, const float* __restrict__ x,
                              int N, int C) {
    extern __shared__ double sh[];          // 2 * 4*C doubles
    int tid = threadIdx.x;
    int c = tid % C, rl = tid / C;
    double s = 0.0, q = 0.0;
    int base = blockIdx.x * 256 + rl * 64;
    for (int it = 0; it < 64; it++) {
        int r = base + it;
        if (r < N) {
            double v = (double)x[(size_t)r * C + c];
            s += v;
            q = fma(v, v, q);
        }
    }
    double* ss = sh;
    double* sq = sh + 4 * C;
    ss[tid] = s; sq[tid] = q;
    __syncthreads();
    if (tid < C) {
        double S = ss[tid] + ss[tid + C] + ss[tid + 2 * C] + ss[tid + 3 * C];
        double Q = sq[tid] + sq[tid + C] + sq[tid + 2 * C] + sq[tid + 3 * C];
        atomicAdd(&st[tid], S);
        atomicAdd(&st[80 + tid], Q);
    }
}

// ---------------- fused LDS-staged tile conv ----------------
// MODE: 0 = plain, 1 = BN-ReLU on staged input, 2 = BN-ReLU input + residual
// accumulate onto out, 3 = per-row attention multiply on staged input.
// Per k-tap: block cooperatively stages TR feature rows (BN/att applied,
// invalid -> 0) + the B x A weight tile into LDS (pitch A+4), then computes
// a TR x B tile. KG>1: taps split across blockIdx.y, fp32 atomicAdd epilogue
// (MODE!=2 pre-zeroed by host; MODE==2 accumulates onto resident out).

template <int A, int B, int TAPS, int TR, int TX, int KG, int MODE>
__launch_bounds__(256)
static __global__ void kconv(float* __restrict__ out, const float* __restrict__ feat,
                             const int* __restrict__ nbr, const float* __restrict__ Wt,
                             const float* __restrict__ att, const double* __restrict__ st,
                             const float* __restrict__ gg, const float* __restrict__ bb,
                             int N, int nstat) {
    constexpr bool BN = (MODE == 1 || MODE == 2);
    constexpr bool ADD = (MODE == 2);
    constexpr bool MUL = (MODE == 3);
    constexpr int A4 = A / 4;
    constexpr int PITCH = A + 4;              // floats; breaks pow-2 bank strides
    constexpr int TY = 256 / TX;
    constexpr int RT = TR / TY;
    constexpr int CT = B / TX;
    constexpr int GQ = TR * A4;
    constexpr int WQ = B * A4;
    constexpr int KPG = (TAPS + KG - 1) / KG;

    __shared__ __attribute__((aligned(16))) float gs[TR * PITCH];
    __shared__ __attribute__((aligned(16))) float wsh[B * PITCH];
    __shared__ float scs[A], bhs[A];

    const int tid = threadIdx.x;
    const int tx = tid % TX, ty = tid / TX;
    const int row0 = blockIdx.x * TR;
    const int k0 = (KG > 1) ? blockIdx.y * KPG : 0;
    const int k1 = (KG > 1) ? ((k0 + KPG < TAPS) ? k0 + KPG : TAPS) : TAPS;
    const float4* f4 = (const float4*)feat;

    if (BN && tid < A) {
        double invN = 1.0 / (double)nstat;
        double mu = st[tid] * invN;
        double var = st[80 + tid] * invN - mu * mu;
        float s = gg[tid] * rsqrtf((float)var + 1e-4f);
        scs[tid] = s;
        bhs[tid] = bb[tid] - (float)mu * s;
    }

    float acc[RT][CT];
#pragma unroll
    for (int i = 0; i < RT; i++) {
        int r = row0 + ty + TY * i;
#pragma unroll
        for (int j = 0; j < CT; j++)
            acc[i][j] = (ADD && KG == 1 && r < N) ? out[(size_t)r * B + tx + TX * j] : 0.0f;
    }

    for (int k = k0; k < k1; k++) {
        __syncthreads();                      // prev-iter LDS reads done (also scs init)
        const float4* wk = (const float4*)(Wt + (size_t)k * B * A);
#pragma unroll
        for (int it = 0; it < (WQ + 255) / 256; it++) {
            int idx = tid + it * 256;
            if (WQ % 256 == 0 || idx < WQ) {
                int br = idx / A4, seg = idx - br * A4;
                *(float4*)&wsh[br * PITCH + seg * 4] = wk[idx];
            }
        }
#pragma unroll
        for (int it = 0; it < (GQ + 255) / 256; it++) {
            int idx = tid + it * 256;
            if (GQ % 256 == 0 || idx < GQ) {
                int rr = idx / A4, seg = idx - rr * A4;
                int r = row0 + rr;
                int id = (r < N) ? nbr[(size_t)r * TAPS + k] : -1;
                float4 v = f4[(size_t)(id < 0 ? 0 : id) * A4 + seg];
                if (BN) {
                    int c0 = seg * 4;
                    v.x = fmaxf(fmaf(v.x, scs[c0 + 0], bhs[c0 + 0]), 0.f);
                    v.y = fmaxf(fmaf(v.y, scs[c0 + 1], bhs[c0 + 1]), 0.f);
                    v.z = fmaxf(fmaf(v.z, scs[c0 + 2], bhs[c0 + 2]), 0.f);
                    v.w = fmaxf(fmaf(v.w, scs[c0 + 3], bhs[c0 + 3]), 0.f);
                }
                if (MUL) {
                    float m = (id < 0) ? 0.f : att[id];
                    v.x *= m; v.y *= m; v.z *= m; v.w *= m;
                }
                if (id < 0) v = make_float4(0.f, 0.f, 0.f, 0.f);
                *(float4*)&gs[rr * PITCH + seg * 4] = v;
            }
        }
        __syncthreads();
#pragma unroll
        for (int ac = 0; ac < A4; ac++) {
            float4 w[CT];
#pragma unroll
            for (int j = 0; j < CT; j++)
                w[j] = *(const float4*)&wsh[(tx + TX * j) * PITCH + ac * 4];
            float4 g[RT];
#pragma unroll
            for (int i = 0; i < RT; i++)
                g[i] = *(const float4*)&gs[(ty + TY * i) * PITCH + ac * 4];
#pragma unroll
            for (int i = 0; i < RT; i++)
#pragma unroll
                for (int j = 0; j < CT; j++) {
                    acc[i][j] = fmaf(g[i].x, w[j].x, acc[i][j]);
                    acc[i][j] = fmaf(g[i].y, w[j].y, acc[i][j]);
                    acc[i][j] = fmaf(g[i].z, w[j].z, acc[i][j]);
                    acc[i][j] = fmaf(g[i].w, w[j].w, acc[i][j]);
                }
        }
    }

#pragma unroll
    for (int i = 0; i < RT; i++) {
        int r = row0 + ty + TY * i;
        if (r < N) {
#pragma unroll
            for (int j = 0; j < CT; j++) {
                if (KG > 1) atomicAdd(&out[(size_t)r * B + tx + TX * j], acc[i][j]);
                else out[(size_t)r * B + tx + TX * j] = acc[i][j];
            }
        }
    }
}

// input layer: A=1, B=16; vectorized over b-quads
static __global__ void kconv_in(float* __restrict__ out, const float* __restrict__ f,
                                const int* __restrict__ nbr, const float* __restrict__ W,
                                int N) {
    int t = blockIdx.x * blockDim.x + threadIdx.x;
    if (t >= N * 4) return;
    int n = t >> 2, bq = t & 3;
    float4 acc = make_float4(0.f, 0.f, 0.f, 0.f);
    const float4* W4 = (const float4*)W;
    for (int k = 0; k < 27; k++) {
        int id = nbr[n * 27 + k];
        if (id < 0) continue;
        float v = f[id];
        float4 w = W4[k * 4 + bq];
        acc.x = fmaf(v, w.x, acc.x);
        acc.y = fmaf(v, w.y, acc.y);
        acc.z = fmaf(v, w.z, acc.z);
        acc.w = fmaf(v, w.w, acc.w);
    }
    ((float4*)out)[n * 4 + bq] = acc;
}

// ---------------- heads / epilogue ----------------

static __global__ void kscores(float* __restrict__ sc, const float* __restrict__ x,
                               const float* __restrict__ w, int N, int C) {
    int n = blockIdx.x * blockDim.x + threadIdx.x;
    if (n >= N) return;
    float s0 = 0.0f, s1 = 0.0f;
    const float* xr = x + (size_t)n * C;
    for (int c = 0; c < C; c++) {
        float v = xr[c];
        s0 = fmaf(v, w[2 * c], s0);
        s1 = fmaf(v, w[2 * c + 1], s1);
    }
    sc[2 * n] = s0;
    sc[2 * n + 1] = s1;
}

// att[n] = softmax(sc[up[n]])[1] > 0.5  <=>  s1 > s0
static __global__ void katt(float* __restrict__ att, const int* __restrict__ up,
                            const float* __restrict__ sc, int N) {
    int n = blockIdx.x * blockDim.x + threadIdx.x;
    if (n >= N) return;
    int p = up[n];
    att[n] = (sc[2 * p + 1] > sc[2 * p]) ? 1.0f : 0.0f;
}

static __global__ void kout0(float* __restrict__ out, const float* __restrict__ z,
                             const float* __restrict__ pw, const float* __restrict__ sw,
                             int N) {
    int n = blockIdx.x * blockDim.x + threadIdx.x;
    if (n >= N) return;
    float o0 = 0, o1 = 0, o2 = 0, o3 = 0, o4 = 0;
    const float* zr = z + (size_t)n * 16;
#pragma unroll
    for (int c = 0; c < 16; c++) {
        float v = zr[c];
        o0 = fmaf(v, pw[3 * c], o0);
        o1 = fmaf(v, pw[3 * c + 1], o1);
        o2 = fmaf(v, pw[3 * c + 2], o2);
        o3 = fmaf(v, sw[2 * c], o3);
        o4 = fmaf(v, sw[2 * c + 1], o4);
    }
    float* r = out + (size_t)n * 5;
    r[0] = o0; r[1] = o1; r[2] = o2; r[3] = o3; r[4] = o4;
}

static __global__ void koutc(float* __restrict__ out, const int* __restrict__ coords,
                             const float* __restrict__ sc, int N) {
    int n = blockIdx.x * blockDim.x + threadIdx.x;
    if (n >= N) return;
    float* r = out + (size_t)n * 5;
    r[0] = (float)coords[3 * n];
    r[1] = (float)coords[3 * n + 1];
    r[2] = (float)coords[3 * n + 2];
    r[3] = sc[2 * n];
    r[4] = sc[2 * n + 1];
}

// ---------------- host-side helpers ----------------

static inline int cdiv(long a, int b) { return (int)((a + b - 1) / b); }

static void conv(hipStream_t s, float* out, const float* feat, const int* nbr,
                 const float* Wt, int N, int A, int B, int TAPS, int mode,
                 const float* att, const double* st, const float* g, const float* b,
                 int nstat) {
#define CASE(AA, BB, TT, TRR, TXX, KGG)                                                    \
    else if (A == AA && B == BB && TAPS == TT) {                                           \
        if (KGG > 1 && mode != 2) hipMemsetAsync(out, 0, (size_t)N * BB * 4, s);           \
        dim3 gr(cdiv(N, TRR), KGG), blk(256);                                              \
        if (mode == 0) kconv<AA, BB, TT, TRR, TXX, KGG, 0><<<gr, blk, 0, s>>>(out, feat, nbr, Wt, att, st, g, b, N, nstat); \
        else if (mode == 1) kconv<AA, BB, TT, TRR, TXX, KGG, 1><<<gr, blk, 0, s>>>(out, feat, nbr, Wt, att, st, g, b, N, nstat); \
        else if (mode == 2) kconv<AA, BB, TT, TRR, TXX, KGG, 2><<<gr, blk, 0, s>>>(out, feat, nbr, Wt, att, st, g, b, N, nstat); \
        else kconv<AA, BB, TT, TRR, TXX, KGG, 3><<<gr, blk, 0, s>>>(out, feat, nbr, Wt, att, st, g, b, N, nstat); \
    }
    if (false) {}
    CASE(16, 16, 27, 128, 8, 2)    // L0 subs + ppn3: 778x2 blocks
    CASE(32, 32, 27, 128, 8, 2)    // L1 subs: 719x2
    CASE(48, 48, 27, 96, 8, 2)     // L2 subs + ppn2: 656x2
    CASE(64, 64, 27, 32, 16, 3)    // L3 subs: 429x3
    CASE(80, 80, 27, 32, 16, 9)    // ppn1: 54x9
    CASE(16, 32, 8, 128, 8, 2)     // down0
    CASE(32, 48, 8, 128, 8, 2)     // down1
    CASE(48, 64, 8, 32, 16, 2)     // down2
    CASE(64, 80, 8, 32, 16, 4)     // down3
#undef CASE
}

extern "C" void kernel_launch(void* const* d_in, const int* in_sizes, int n_in,
                              void* d_out, int out_size, void* d_ws, size_t ws_size,
                              hipStream_t stream) {
    (void)n_in; (void)out_size; (void)ws_size;
    const int SL[5] = {192, 96, 48, 24, 12};
    const int C[5] = {16, 32, 48, 64, 80};
    int N[5];
    const int* coords[5];
    for (int l = 0; l < 5; l++) { N[l] = in_sizes[l] / 3; coords[l] = (const int*)d_in[l]; }
    const float* features = (const float*)d_in[5];
    const float* w_in = (const float*)d_in[6];
    const float *blk_w[4], *blk_g[4], *blk_b[4], *dn_g[4], *dn_b[4], *dn_w[4];
    for (int i = 0; i < 4; i++) {
        blk_w[i] = (const float*)d_in[7 + 6 * i];
        blk_g[i] = (const float*)d_in[8 + 6 * i];
        blk_b[i] = (const float*)d_in[9 + 6 * i];
        dn_g[i] = (const float*)d_in[10 + 6 * i];
        dn_b[i] = (const float*)d_in[11 + 6 * i];
        dn_w[i] = (const float*)d_in[12 + 6 * i];
    }
    const float* ppn1_w  = (const float*)d_in[31];
    const float* ppn1_sw = (const float*)d_in[32];
    const float* ppn2_w  = (const float*)d_in[33];
    const float* ppn2_sw = (const float*)d_in[34];
    const float* ppn3_w  = (const float*)d_in[35];
    const float* ppn3_pw = (const float*)d_in[36];
    const float* ppn3_sw = (const float*)d_in[37];
    float* dout = (float*)d_out;

    // ---- workspace layout ----
    char* ws = (char*)d_ws;
    size_t off = 0;
    auto alloc = [&](size_t bytes) -> char* {
        off = (off + 255) & ~(size_t)255;
        char* p = ws + off;
        off += bytes;
        return p;
    };
    int* nbr[5];
    for (int l = 0; l < 5; l++) nbr[l] = (int*)alloc((size_t)N[l] * 27 * 4);
    int* down8[4];
    for (int i = 0; i < 4; i++) down8[i] = (int*)alloc((size_t)N[i + 1] * 8 * 4);
    int* up1 = (int*)alloc((size_t)N[2] * 4);
    int* up2 = (int*)alloc((size_t)N[0] * 4);
    double* stats = (double*)alloc(26 * 160 * sizeof(double));
    float* blkWt[4];
    float* dnWt[4];
    for (int i = 0; i < 4; i++) {
        blkWt[i] = (float*)alloc((size_t)108 * C[i] * C[i] * 4);
        dnWt[i] = (float*)alloc((size_t)8 * C[i] * C[i + 1] * 4);
    }
    float* p1Wt = (float*)alloc((size_t)27 * 80 * 80 * 4);
    float* p2Wt = (float*)alloc((size_t)27 * 48 * 48 * 4);
    float* p3Wt = (float*)alloc((size_t)27 * 16 * 16 * 4);
    float* fmap0 = (float*)alloc((size_t)N[0] * 16 * 4);
    float* fmap2 = (float*)alloc((size_t)N[2] * 48 * 4);
    float* sc1 = (float*)alloc((size_t)N[4] * 2 * 4);
    float* sc2 = (float*)alloc((size_t)N[2] * 2 * 4);
    float* att1 = (float*)alloc((size_t)N[2] * 4);
    float* att2 = (float*)alloc((size_t)N[0] * 4);

    // transient region: grids (phase 1) alias the 2 rotating feature buffers (phase 2)
    size_t BIG = 0;
    for (int l = 0; l < 5; l++) {
        size_t s = (size_t)N[l] * C[l] * 4;
        if (s > BIG) BIG = s;
    }
    BIG = (BIG + 255) & ~(size_t)255;
    off = (off + 255) & ~(size_t)255;
    size_t trans = off;
    int* grid[5];
    size_t gtot = 0;
    for (int l = 0; l < 5; l++) {
        grid[l] = (int*)(ws + trans + gtot);
        gtot += (size_t)SL[l] * SL[l] * SL[l] * 4;
    }
    float* B0 = (float*)(ws + trans);
    float* B1 = (float*)(ws + trans + BIG);

    // ---- phase 1: index structures + weight transposes + stats zero ----
    hipMemsetAsync(ws + trans, 0xFF, gtot, stream);  // all grids = -1
    hipMemsetAsync(stats, 0, 26 * 160 * sizeof(double), stream);
    for (int l = 0; l < 5; l++)
        kscatter<<<cdiv(N[l], TPB), TPB, 0, stream>>>(grid[l], coords[l], N[l], SL[l]);
    for (int l = 0; l < 5; l++)
        knbr27<<<cdiv((long)N[l] * 27, TPB), TPB, 0, stream>>>(nbr[l], coords[l], grid[l], N[l], SL[l]);
    for (int i = 0; i < 4; i++)
        kdown8<<<cdiv((long)N[i + 1] * 8, TPB), TPB, 0, stream>>>(down8[i], coords[i + 1], grid[i], N[i + 1], SL[i]);
    kup<<<cdiv(N[2], TPB), TPB, 0, stream>>>(up1, coords[2], grid[4], N[2], 12);
    kup<<<cdiv(N[0], TPB), TPB, 0, stream>>>(up2, coords[0], grid[2], N[0], 48);
    for (int i = 0; i < 4; i++) {
        int n1 = 108 * C[i] * C[i];
        ktrans<<<cdiv(n1, TPB), TPB, 0, stream>>>(blkWt[i], blk_w[i], 108, C[i], C[i]);
        int n2 = 8 * C[i] * C[i + 1];
        ktrans<<<cdiv(n2, TPB), TPB, 0, stream>>>(dnWt[i], dn_w[i], 8, C[i], C[i + 1]);
    }
    ktrans<<<cdiv(27 * 6400, TPB), TPB, 0, stream>>>(p1Wt, ppn1_w, 27, 80, 80);
    ktrans<<<cdiv(27 * 2304, TPB), TPB, 0, stream>>>(p2Wt, ppn2_w, 27, 48, 48);
    ktrans<<<cdiv(27 * 256, TPB), TPB, 0, stream>>>(p3Wt, ppn3_w, 27, 16, 16);

    // ---- phase 2: network (grids dead; B0/B1 alias that memory) ----
    int slot = 0;
    auto st = [&]() { return stats + 160 * (slot++); };

    float* X = B0;
    float* Y = B1;
    kconv_in<<<cdiv((long)N[0] * 4, TPB), TPB, 0, stream>>>(X, features, nbr[0], w_in, N[0]);
    hipMemcpyAsync(fmap0, X, (size_t)N[0] * 16 * 4, hipMemcpyDeviceToDevice, stream);

    for (int i = 0; i < 4; i++) {
        int Ni = N[i], Ci = C[i];
        int shb = 8 * Ci * 2 * (int)sizeof(double);
        for (int r = 0; r < 2; r++) {
            const float* w0 = blkWt[i] + (size_t)(2 * r) * 27 * Ci * Ci;
            const float* w1 = blkWt[i] + (size_t)(2 * r + 1) * 27 * Ci * Ci;
            double* s0 = st();
            kstats<<<cdiv(Ni, 256), 4 * Ci, shb, stream>>>(s0, X, Ni, Ci);
            conv(stream, Y, X, nbr[i], w0, Ni, Ci, Ci, 27, 1, nullptr,
                 s0, blk_g[i] + (2 * r) * Ci, blk_b[i] + (2 * r) * Ci, Ni);
            double* s1 = st();
            kstats<<<cdiv(Ni, 256), 4 * Ci, shb, stream>>>(s1, Y, Ni, Ci);
            conv(stream, X, Y, nbr[i], w1, Ni, Ci, Ci, 27, 2, nullptr,
                 s1, blk_g[i] + (2 * r + 1) * Ci, blk_b[i] + (2 * r + 1) * Ci, Ni);
        }
        double* s4 = st();
        kstats<<<cdiv(Ni, 256), 4 * Ci, shb, stream>>>(s4, X, Ni, Ci);
        conv(stream, Y, X, down8[i], dnWt[i], N[i + 1], Ci, C[i + 1], 8, 1, nullptr,
             s4, dn_g[i], dn_b[i], Ni);
        if (i == 1)
            hipMemcpyAsync(fmap2, Y, (size_t)N[2] * 48 * 4, hipMemcpyDeviceToDevice, stream);
        float* t = X; X = Y; Y = t;
    }

    // ---- heads ----  (X = level-4 features)
    conv(stream, Y, X, nbr[4], p1Wt, N[4], 80, 80, 27, 0, nullptr, nullptr, nullptr, nullptr, N[4]);
    kscores<<<cdiv(N[4], TPB), TPB, 0, stream>>>(sc1, Y, ppn1_sw, N[4], 80);
    koutc<<<cdiv(N[4], TPB), TPB, 0, stream>>>(dout + (size_t)N[0] * 5, coords[4], sc1, N[4]);
    // ppn2 @ level 2 (attention multiply fused into staging)
    katt<<<cdiv(N[2], TPB), TPB, 0, stream>>>(att1, up1, sc1, N[2]);
    conv(stream, X, fmap2, nbr[2], p2Wt, N[2], 48, 48, 27, 3, att1, nullptr, nullptr, nullptr, N[2]);
    kscores<<<cdiv(N[2], TPB), TPB, 0, stream>>>(sc2, X, ppn2_sw, N[2], 48);
    koutc<<<cdiv(N[2], TPB), TPB, 0, stream>>>(dout + (size_t)(N[0] + N[4]) * 5, coords[2], sc2, N[2]);
    // ppn3 @ level 0
    katt<<<cdiv(N[0], TPB), TPB, 0, stream>>>(att2, up2, sc2, N[0]);
    conv(stream, Y, fmap0, nbr[0], p3Wt, N[0], 16, 16, 27, 3, att2, nullptr, nullptr, nullptr, N[0]);
    kout0<<<cdiv(N[0], TPB), TPB, 0, stream>>>(dout, Y, ppn3_pw, ppn3_sw, N[0]);
}